// Round 1
// baseline (1736.990 us; speedup 1.0000x reference)
//
#include <hip/hip_runtime.h>

#define B 2
#define T 2048
#define HID 1536
#define NH 12
#define DK 16
#define DV 128
#define BT (B * T)
#define EPS 1e-12f

// ---------------------------------------------------------------------------
// C[M,N] = A[M,K] @ B[N,K]^T   (torch Linear).  fp32, 128x128 tile, BK=8,
// 8x8 per thread, K-major LDS layout so inner loop uses ds_read_b128.
// M must be multiple of 128; K multiple of 8; N guarded (multiple of 4).
// ---------------------------------------------------------------------------
__global__ __launch_bounds__(256) void gemm_nt_f32(const float* __restrict__ A,
                                                   const float* __restrict__ Bm,
                                                   float* __restrict__ C,
                                                   int M, int N, int K) {
    __shared__ float As[8][132];
    __shared__ float Bs[8][132];
    const int tid = threadIdx.x;
    const int m0 = blockIdx.y * 128;
    const int n0 = blockIdx.x * 128;
    const int ty = tid >> 4;        // 0..15 -> row group
    const int tx = tid & 15;        // 0..15 -> col group
    const int lr = tid >> 1;        // 0..127 tile row for loads
    const int lc = (tid & 1) * 4;   // k offset 0 or 4

    float acc[8][8];
#pragma unroll
    for (int i = 0; i < 8; ++i)
#pragma unroll
        for (int j = 0; j < 8; ++j) acc[i][j] = 0.f;

    for (int k0 = 0; k0 < K; k0 += 8) {
        float4 av = *reinterpret_cast<const float4*>(&A[(size_t)(m0 + lr) * K + k0 + lc]);
        float4 bv = make_float4(0.f, 0.f, 0.f, 0.f);
        const int bn = n0 + lr;
        if (bn < N)
            bv = *reinterpret_cast<const float4*>(&Bm[(size_t)bn * K + k0 + lc]);
        As[lc + 0][lr] = av.x; As[lc + 1][lr] = av.y;
        As[lc + 2][lr] = av.z; As[lc + 3][lr] = av.w;
        Bs[lc + 0][lr] = bv.x; Bs[lc + 1][lr] = bv.y;
        Bs[lc + 2][lr] = bv.z; Bs[lc + 3][lr] = bv.w;
        __syncthreads();
#pragma unroll
        for (int kk = 0; kk < 8; ++kk) {
            float a[8], b[8];
            *(float4*)&a[0] = *(const float4*)&As[kk][ty * 8];
            *(float4*)&a[4] = *(const float4*)&As[kk][ty * 8 + 4];
            *(float4*)&b[0] = *(const float4*)&Bs[kk][tx * 8];
            *(float4*)&b[4] = *(const float4*)&Bs[kk][tx * 8 + 4];
#pragma unroll
            for (int i = 0; i < 8; ++i)
#pragma unroll
                for (int j = 0; j < 8; ++j)
                    acc[i][j] += a[i] * b[j];
        }
        __syncthreads();
    }

#pragma unroll
    for (int i = 0; i < 8; ++i) {
        const int m = m0 + ty * 8 + i;
#pragma unroll
        for (int j4 = 0; j4 < 8; j4 += 4) {
            const int n = n0 + tx * 8 + j4;
            if (n < N) {
                *(float4*)&C[(size_t)m * N + n] =
                    make_float4(acc[i][j4], acc[i][j4 + 1], acc[i][j4 + 2], acc[i][j4 + 3]);
            }
        }
    }
}

// ---------------------------------------------------------------------------
// Flash-style causal linear attention with collapsed Taylor features:
//   S[t,s] = 1 + a/4 + a^2/32,  a = q_t . k_s   (16-dim dot)
//   num_t  = sum_{s<=t} S[t,s] v_s ;  den_t = sum_{s<=t} S[t,s] + eps
//   y_t    = num_t / den_t
// One block per (b, h, 64-row q tile). 256 threads.
// q,k layout: [b*t, 192] row-major (head h at col h*16)
// v,y layout: [b*t, 1536] row-major (head h at col h*128)
// ---------------------------------------------------------------------------
__global__ __launch_bounds__(256) void based_attn_f32(const float* __restrict__ qb,
                                                      const float* __restrict__ kb,
                                                      const float* __restrict__ vb,
                                                      float* __restrict__ yb) {
    const int qt = blockIdx.x;   // 0..31
    const int h  = blockIdx.y;   // 0..11
    const int bi = blockIdx.z;   // 0..1
    const int tid = threadIdx.x;

    __shared__ float qs[64][17];
    __shared__ float ks[64][17];
    __shared__ float vs[64][DV];      // 32 KB
    __shared__ float ss[64][65];

    // load Q tile: row r of tile -> global row bi*T + qt*64 + r, cols h*16..+15
    {
        const int r = tid >> 2;
        const int c = (tid & 3) * 4;
        float4 v = *reinterpret_cast<const float4*>(
            &qb[(size_t)(bi * T + qt * 64 + r) * (NH * DK) + h * DK + c]);
        qs[r][c + 0] = v.x; qs[r][c + 1] = v.y; qs[r][c + 2] = v.z; qs[r][c + 3] = v.w;
    }

    // per-thread output accumulators: 2 rows x 16 cols
    const int rr = tid >> 3;          // 0..31 (rows rr and rr+32)
    const int cc = (tid & 7) * 16;    // col base within head
    float n1[16], n2[16];
#pragma unroll
    for (int j = 0; j < 16; ++j) { n1[j] = 0.f; n2[j] = 0.f; }
    float den1 = 0.f, den2 = 0.f;

    for (int kt = 0; kt <= qt; ++kt) {
        __syncthreads();  // previous stage B done (and Q visible on iter 0)

        // load K tile
        {
            const int r = tid >> 2;
            const int c = (tid & 3) * 4;
            float4 v = *reinterpret_cast<const float4*>(
                &kb[(size_t)(bi * T + kt * 64 + r) * (NH * DK) + h * DK + c]);
            ks[r][c + 0] = v.x; ks[r][c + 1] = v.y; ks[r][c + 2] = v.z; ks[r][c + 3] = v.w;
        }
        // load V tile: 64 x 128 floats = 2048 float4, 8 per thread
#pragma unroll
        for (int u = 0; u < 8; ++u) {
            const int idx = tid + u * 256;
            const int r = idx >> 5;
            const int c = (idx & 31) * 4;
            float4 v = *reinterpret_cast<const float4*>(
                &vb[(size_t)(bi * T + kt * 64 + r) * (NH * DV) + h * DV + c]);
            *(float4*)&vs[r][c] = v;
        }
        __syncthreads();

        // stage A: S tile. thread -> row i = tid/4, cols (tid%4)*16 .. +15
        {
            const int i = tid >> 2;
            const int jb = (tid & 3) * 16;
            const bool diag = (kt == qt);
#pragma unroll
            for (int jj = 0; jj < 16; ++jj) {
                const int j = jb + jj;
                float a = 0.f;
#pragma unroll
                for (int c = 0; c < DK; ++c) a += qs[i][c] * ks[j][c];
                float s = 1.f + 0.25f * a + a * a * (1.f / 32.f);
                if (diag && j > i) s = 0.f;
                ss[i][j] = s;
            }
        }
        __syncthreads();

        // stage B: num += S @ V, den += rowsum(S)
        for (int s = 0; s < 64; ++s) {
            const float w1 = ss[rr][s];
            const float w2 = ss[rr + 32][s];
            den1 += w1; den2 += w2;
            const float* vrow = &vs[s][cc];
            float4 va = *(const float4*)&vrow[0];
            float4 vb4 = *(const float4*)&vrow[4];
            float4 vc = *(const float4*)&vrow[8];
            float4 vd = *(const float4*)&vrow[12];
            n1[0]  += w1 * va.x;  n1[1]  += w1 * va.y;  n1[2]  += w1 * va.z;  n1[3]  += w1 * va.w;
            n1[4]  += w1 * vb4.x; n1[5]  += w1 * vb4.y; n1[6]  += w1 * vb4.z; n1[7]  += w1 * vb4.w;
            n1[8]  += w1 * vc.x;  n1[9]  += w1 * vc.y;  n1[10] += w1 * vc.z;  n1[11] += w1 * vc.w;
            n1[12] += w1 * vd.x;  n1[13] += w1 * vd.y;  n1[14] += w1 * vd.z;  n1[15] += w1 * vd.w;
            n2[0]  += w2 * va.x;  n2[1]  += w2 * va.y;  n2[2]  += w2 * va.z;  n2[3]  += w2 * va.w;
            n2[4]  += w2 * vb4.x; n2[5]  += w2 * vb4.y; n2[6]  += w2 * vb4.z; n2[7]  += w2 * vb4.w;
            n2[8]  += w2 * vc.x;  n2[9]  += w2 * vc.y;  n2[10] += w2 * vc.z;  n2[11] += w2 * vc.w;
            n2[12] += w2 * vd.x;  n2[13] += w2 * vd.y;  n2[14] += w2 * vd.z;  n2[15] += w2 * vd.w;
        }
    }

    // write y rows rr and rr+32
    const float rd1 = 1.f / (den1 + EPS);
    const float rd2 = 1.f / (den2 + EPS);
    {
        float* y1 = &yb[(size_t)(bi * T + qt * 64 + rr) * (NH * DV) + h * DV + cc];
        float* y2 = &yb[(size_t)(bi * T + qt * 64 + rr + 32) * (NH * DV) + h * DV + cc];
#pragma unroll
        for (int j4 = 0; j4 < 16; j4 += 4) {
            *(float4*)&y1[j4] = make_float4(n1[j4] * rd1, n1[j4 + 1] * rd1,
                                            n1[j4 + 2] * rd1, n1[j4 + 3] * rd1);
            *(float4*)&y2[j4] = make_float4(n2[j4] * rd2, n2[j4 + 1] * rd2,
                                            n2[j4 + 2] * rd2, n2[j4 + 3] * rd2);
        }
    }
}

extern "C" void kernel_launch(void* const* d_in, const int* in_sizes, int n_in,
                              void* d_out, int out_size, void* d_ws, size_t ws_size,
                              hipStream_t stream) {
    (void)in_sizes; (void)n_in; (void)out_size; (void)ws_size;
    const float* hs = (const float*)d_in[0];  // [4096, 1536]
    const float* Wq = (const float*)d_in[1];  // [192, 1536]
    const float* Wk = (const float*)d_in[2];  // [192, 1536]
    const float* Wv = (const float*)d_in[3];  // [1536, 1536]
    const float* Wo = (const float*)d_in[4];  // [1536, 1536]
    float* out = (float*)d_out;               // [4096, 1536]

    float* ws = (float*)d_ws;
    float* qb = ws;                                  // 4096*192
    float* kb = qb + (size_t)BT * NH * DK;           // 4096*192
    float* vb = kb + (size_t)BT * NH * DK;           // 4096*1536
    float* yb = vb + (size_t)BT * NH * DV;           // 4096*1536

    // projections: X @ W^T
    dim3 blk(256);
    dim3 gqk((NH * DK + 127) / 128, BT / 128);       // (2, 32)
    gemm_nt_f32<<<gqk, blk, 0, stream>>>(hs, Wq, qb, BT, NH * DK, HID);
    gemm_nt_f32<<<gqk, blk, 0, stream>>>(hs, Wk, kb, BT, NH * DK, HID);
    dim3 gv(HID / 128, BT / 128);                    // (12, 32)
    gemm_nt_f32<<<gv, blk, 0, stream>>>(hs, Wv, vb, BT, NH * DV, HID);

    // causal taylor linear attention
    based_attn_f32<<<dim3(T / 64, NH, B), blk, 0, stream>>>(qb, kb, vb, yb);

    // output projection
    gemm_nt_f32<<<gv, blk, 0, stream>>>(yb, Wo, out, BT, HID, HID);
}

// Round 2
// 828.965 us; speedup vs baseline: 2.0954x; 2.0954x over previous
//
#include <hip/hip_runtime.h>

#define B 2
#define T 2048
#define HID 1536
#define NH 12
#define DK 16
#define DV 128
#define BT (B * T)
#define EPS 1e-12f

typedef __attribute__((ext_vector_type(8))) short bf16x8;
typedef __attribute__((ext_vector_type(4))) float f32x4;

__device__ __forceinline__ unsigned short f2bf(float f) {
    unsigned int u = __float_as_uint(f);
    u += 0x7FFFu + ((u >> 16) & 1u);
    return (unsigned short)(u >> 16);
}

// ---------------------------------------------------------------------------
// fp32 -> bf16 (RNE), n multiple of 8
// ---------------------------------------------------------------------------
__global__ __launch_bounds__(256) void cvt_bf16(const float* __restrict__ in,
                                                unsigned short* __restrict__ out, int n) {
    int i = (blockIdx.x * 256 + threadIdx.x) * 8;
    if (i >= n) return;
    float4 a = *(const float4*)(in + i);
    float4 b = *(const float4*)(in + i + 4);
    ushort4 o0 = make_ushort4(f2bf(a.x), f2bf(a.y), f2bf(a.z), f2bf(a.w));
    ushort4 o1 = make_ushort4(f2bf(b.x), f2bf(b.y), f2bf(b.z), f2bf(b.w));
    *(ushort4*)(out + i) = o0;
    *(ushort4*)(out + i + 4) = o1;
}

// ---------------------------------------------------------------------------
// C[M,N] = A[M,K] @ B[N,K]^T, A/B bf16, C fp32.  m97 structure:
// 128x128 tile, BK=32, global_load_lds width=16, 16x16x32 bf16 MFMA,
// 4 waves each computing a 64x64 quadrant (4x4 frags).
// M%128==0, K%32==0. N guarded on store; B must be READABLE up to
// ceil(N/128)*128 rows (pad the buffer).
// ---------------------------------------------------------------------------
__global__ __launch_bounds__(256) void gemm_bf16_nt(const unsigned short* __restrict__ A,
                                                    const unsigned short* __restrict__ Bm,
                                                    float* __restrict__ C,
                                                    int M, int N, int K) {
    __shared__ unsigned short As[128 * 32];
    __shared__ unsigned short Bs[128 * 32];
    const int tid = threadIdx.x;
    const int m0 = blockIdx.y * 128;
    const int n0 = blockIdx.x * 128;
    const int wave = tid >> 6, lane = tid & 63;
    const int wm = (wave & 1) * 64, wn = (wave >> 1) * 64;
    const int fr = lane & 15;          // row within 16 (A: m, B: n)
    const int fk = (lane >> 4) * 8;    // k offset

    f32x4 acc[4][4];
#pragma unroll
    for (int i = 0; i < 4; ++i)
#pragma unroll
        for (int j = 0; j < 4; ++j) acc[i][j] = (f32x4)0.f;

    // staging chunks: 512 x 16B per tile; thread handles chunks tid, tid+256
    const int c0 = tid, c1 = tid + 256;
    const int r0 = c0 >> 2, q0 = (c0 & 3) * 8;
    const int r1 = c1 >> 2, q1 = (c1 & 3) * 8;

    for (int k0 = 0; k0 < K; k0 += 32) {
        __builtin_amdgcn_global_load_lds(
            (const __attribute__((address_space(1))) void*)(A + (size_t)(m0 + r0) * K + k0 + q0),
            (__attribute__((address_space(3))) void*)(As + c0 * 8), 16, 0, 0);
        __builtin_amdgcn_global_load_lds(
            (const __attribute__((address_space(1))) void*)(A + (size_t)(m0 + r1) * K + k0 + q1),
            (__attribute__((address_space(3))) void*)(As + c1 * 8), 16, 0, 0);
        __builtin_amdgcn_global_load_lds(
            (const __attribute__((address_space(1))) void*)(Bm + (size_t)(n0 + r0) * K + k0 + q0),
            (__attribute__((address_space(3))) void*)(Bs + c0 * 8), 16, 0, 0);
        __builtin_amdgcn_global_load_lds(
            (const __attribute__((address_space(1))) void*)(Bm + (size_t)(n0 + r1) * K + k0 + q1),
            (__attribute__((address_space(3))) void*)(Bs + c1 * 8), 16, 0, 0);
        __syncthreads();

        bf16x8 af[4], bfr[4];
#pragma unroll
        for (int mb = 0; mb < 4; ++mb)
            af[mb] = *(const bf16x8*)(As + (wm + mb * 16 + fr) * 32 + fk);
#pragma unroll
        for (int nb = 0; nb < 4; ++nb)
            bfr[nb] = *(const bf16x8*)(Bs + (wn + nb * 16 + fr) * 32 + fk);
#pragma unroll
        for (int mb = 0; mb < 4; ++mb)
#pragma unroll
            for (int nb = 0; nb < 4; ++nb)
                acc[mb][nb] = __builtin_amdgcn_mfma_f32_16x16x32_bf16(
                    af[mb], bfr[nb], acc[mb][nb], 0, 0, 0);
        __syncthreads();
    }

    // epilogue: C/D layout col = lane&15, row = (lane>>4)*4 + reg
    const int orow = (lane >> 4) * 4;
#pragma unroll
    for (int nb = 0; nb < 4; ++nb) {
        const int col = n0 + wn + nb * 16 + fr;
        if (col < N) {
#pragma unroll
            for (int mb = 0; mb < 4; ++mb) {
                const int row = m0 + wm + mb * 16 + orow;
#pragma unroll
                for (int r = 0; r < 4; ++r)
                    C[(size_t)(row + r) * N + col] = acc[mb][nb][r];
            }
        }
    }
}

// ---------------------------------------------------------------------------
// Causal Taylor linear attention, collapsed features:
//   S = 1 + a/4 + a^2/32, a = q.k (16-dim); y = (S@V) / rowsum(S)
// fp32 math, bf16 output (feeds bf16 out-proj GEMM).
// Block = (b, h, 64-row q-tile); heavy tiles (large qt) scheduled first.
// Stage B mapping: thread owns 4 rows (rr+16m) x 8 cols (cb..cb+3, cb+64..+67)
// -> vs reads cover all 32 banks 2-way (conflict-free).
// ---------------------------------------------------------------------------
__global__ __launch_bounds__(256) void based_attn_f32(const float* __restrict__ qb,
                                                      const float* __restrict__ kb,
                                                      const float* __restrict__ vb,
                                                      unsigned short* __restrict__ ybb) {
    const int qt = (T / 64 - 1) - blockIdx.x;  // heavy blocks first
    const int h  = blockIdx.y;
    const int bi = blockIdx.z;
    const int tid = threadIdx.x;

    __shared__ float qs[64][20];
    __shared__ float ks[64][16];
    __shared__ float vs[64][DV];
    __shared__ float ss[64][65];

    // load Q tile
    {
        const int r = tid >> 2;
        const int c = (tid & 3) * 4;
        float4 v = *(const float4*)&qb[(size_t)(bi * T + qt * 64 + r) * (NH * DK) + h * DK + c];
        *(float4*)&qs[r][c] = v;
    }

    const int rr = tid >> 4;         // 0..15
    const int cb = (tid & 15) * 4;   // 0..60
    float nacc[4][8];
    float den[4] = {0.f, 0.f, 0.f, 0.f};
#pragma unroll
    for (int m = 0; m < 4; ++m)
#pragma unroll
        for (int j = 0; j < 8; ++j) nacc[m][j] = 0.f;

    for (int kt = 0; kt <= qt; ++kt) {
        __syncthreads();  // prev stage B done; Q visible on iter 0

        {   // K tile
            const int r = tid >> 2;
            const int c = (tid & 3) * 4;
            float4 v = *(const float4*)&kb[(size_t)(bi * T + kt * 64 + r) * (NH * DK) + h * DK + c];
            *(float4*)&ks[r][c] = v;
        }
#pragma unroll
        for (int u = 0; u < 8; ++u) {  // V tile: 64x128 f32
            const int idx = tid + u * 256;
            const int r = idx >> 5;
            const int c = (idx & 31) * 4;
            *(float4*)&vs[r][c] =
                *(const float4*)&vb[(size_t)(bi * T + kt * 64 + r) * (NH * DV) + h * DV + c];
        }
        __syncthreads();

        {   // stage A: S tile (row i, 16-col strip)
            const int i = tid >> 2;
            const int jb = (tid & 3) * 16;
            const float4 a0 = *(const float4*)&qs[i][0];
            const float4 a1 = *(const float4*)&qs[i][4];
            const float4 a2 = *(const float4*)&qs[i][8];
            const float4 a3 = *(const float4*)&qs[i][12];
            const bool diag = (kt == qt);
#pragma unroll
            for (int jj = 0; jj < 16; ++jj) {
                const int j = jb + jj;
                const float4 b0 = *(const float4*)&ks[j][0];
                const float4 b1 = *(const float4*)&ks[j][4];
                const float4 b2 = *(const float4*)&ks[j][8];
                const float4 b3 = *(const float4*)&ks[j][12];
                float a = a0.x * b0.x + a0.y * b0.y + a0.z * b0.z + a0.w * b0.w
                        + a1.x * b1.x + a1.y * b1.y + a1.z * b1.z + a1.w * b1.w
                        + a2.x * b2.x + a2.y * b2.y + a2.z * b2.z + a2.w * b2.w
                        + a3.x * b3.x + a3.y * b3.y + a3.z * b3.z + a3.w * b3.w;
                float s = 1.f + 0.25f * a + a * a * (1.f / 32.f);
                if (diag && j > i) s = 0.f;
                ss[i][j] = s;
            }
        }
        __syncthreads();

        // stage B: num += S@V, den += rowsum(S)
#pragma unroll 4
        for (int s = 0; s < 64; ++s) {
            const float4 v0 = *(const float4*)&vs[s][cb];
            const float4 v1 = *(const float4*)&vs[s][cb + 64];
#pragma unroll
            for (int m = 0; m < 4; ++m) {
                const float w = ss[rr + 16 * m][s];
                den[m] += w;
                nacc[m][0] += w * v0.x; nacc[m][1] += w * v0.y;
                nacc[m][2] += w * v0.z; nacc[m][3] += w * v0.w;
                nacc[m][4] += w * v1.x; nacc[m][5] += w * v1.y;
                nacc[m][6] += w * v1.z; nacc[m][7] += w * v1.w;
            }
        }
    }

    // epilogue: y rows rr+16m, bf16
#pragma unroll
    for (int m = 0; m < 4; ++m) {
        const size_t row = (size_t)(bi * T + qt * 64 + rr + 16 * m);
        const float rd = 1.f / (den[m] + EPS);
        ushort4 o0 = make_ushort4(f2bf(nacc[m][0] * rd), f2bf(nacc[m][1] * rd),
                                  f2bf(nacc[m][2] * rd), f2bf(nacc[m][3] * rd));
        ushort4 o1 = make_ushort4(f2bf(nacc[m][4] * rd), f2bf(nacc[m][5] * rd),
                                  f2bf(nacc[m][6] * rd), f2bf(nacc[m][7] * rd));
        *(ushort4*)&ybb[row * (NH * DV) + h * DV + cb] = o0;
        *(ushort4*)&ybb[row * (NH * DV) + h * DV + cb + 64] = o1;
    }
}

extern "C" void kernel_launch(void* const* d_in, const int* in_sizes, int n_in,
                              void* d_out, int out_size, void* d_ws, size_t ws_size,
                              hipStream_t stream) {
    (void)in_sizes; (void)n_in; (void)out_size; (void)ws_size;
    const float* hs = (const float*)d_in[0];  // [4096, 1536]
    const float* Wq = (const float*)d_in[1];  // [192, 1536]
    const float* Wk = (const float*)d_in[2];  // [192, 1536]
    const float* Wv = (const float*)d_in[3];  // [1536, 1536]
    const float* Wo = (const float*)d_in[4];  // [1536, 1536]
    float* out = (float*)d_out;               // [4096, 1536]

    // ws layout (55.0 MB total; round-1 proved >= 56.6 MB available)
    float* wsf = (float*)d_ws;
    float* qb = wsf;                                   // 4096*192 f32
    float* kb = qb + (size_t)BT * NH * DK;
    float* vb = kb + (size_t)BT * NH * DK;             // 4096*1536 f32
    unsigned short* hsb = (unsigned short*)(vb + (size_t)BT * NH * DV);  // 4096*1536 bf16
    unsigned short* ybb = hsb;                         // alias: hs dead after V GEMM
    unsigned short* wqb = hsb + (size_t)BT * HID;      // 256*1536 (padded rows 192..255)
    unsigned short* wkb = wqb + 256 * HID;
    unsigned short* wvb = wkb + 256 * HID;             // 1536*1536
    unsigned short* wob = wvb + (size_t)HID * HID;

    dim3 blk(256);
    cvt_bf16<<<dim3(BT * HID / 8 / 256), blk, 0, stream>>>(hs, hsb, BT * HID);
    cvt_bf16<<<dim3(NH * DK * HID / 8 / 256), blk, 0, stream>>>(Wq, wqb, NH * DK * HID);
    cvt_bf16<<<dim3(NH * DK * HID / 8 / 256), blk, 0, stream>>>(Wk, wkb, NH * DK * HID);
    cvt_bf16<<<dim3(HID * HID / 8 / 256), blk, 0, stream>>>(Wv, wvb, HID * HID);
    cvt_bf16<<<dim3(HID * HID / 8 / 256), blk, 0, stream>>>(Wo, wob, HID * HID);

    gemm_bf16_nt<<<dim3(2, 32), blk, 0, stream>>>(hsb, wqb, qb, BT, NH * DK, HID);
    gemm_bf16_nt<<<dim3(2, 32), blk, 0, stream>>>(hsb, wkb, kb, BT, NH * DK, HID);
    gemm_bf16_nt<<<dim3(12, 32), blk, 0, stream>>>(hsb, wvb, vb, BT, NH * DV, HID);

    based_attn_f32<<<dim3(T / 64, NH, B), blk, 0, stream>>>(qb, kb, vb, ybb);

    gemm_bf16_nt<<<dim3(12, 32), blk, 0, stream>>>(ybb, wob, out, BT, HID, HID);
}

// Round 3
// 313.313 us; speedup vs baseline: 5.5439x; 2.6458x over previous
//
#include <hip/hip_runtime.h>

#define B 2
#define T 2048
#define HID 1536
#define NH 12
#define DK 16
#define DV 128
#define BT (B * T)
#define EPS 1e-12f

typedef __attribute__((ext_vector_type(8))) short bf16x8;
typedef __attribute__((ext_vector_type(4))) float f32x4;

__device__ __forceinline__ unsigned short f2bf(float f) {
    unsigned int u = __float_as_uint(f);
    u += 0x7FFFu + ((u >> 16) & 1u);
    return (unsigned short)(u >> 16);
}

// ---------------------------------------------------------------------------
// fp32 -> bf16 (RNE), n multiple of 8
// ---------------------------------------------------------------------------
__global__ __launch_bounds__(256) void cvt_bf16(const float* __restrict__ in,
                                                unsigned short* __restrict__ out, int n) {
    int i = (blockIdx.x * 256 + threadIdx.x) * 8;
    if (i >= n) return;
    float4 a = *(const float4*)(in + i);
    float4 b = *(const float4*)(in + i + 4);
    *(ushort4*)(out + i)     = make_ushort4(f2bf(a.x), f2bf(a.y), f2bf(a.z), f2bf(a.w));
    *(ushort4*)(out + i + 4) = make_ushort4(f2bf(b.x), f2bf(b.y), f2bf(b.z), f2bf(b.w));
}

// ---------------------------------------------------------------------------
// C[M,N] = A[M,K] @ B[N,K]^T, A/B bf16.  m97 structure: 128x128 tile, BK=32,
// global_load_lds width=16, 16x16x32 bf16 MFMA, 4 waves x 4x4 frags.
// MODE 0: C fp32 row-major.  MODE 1: C bf16 row-major.
// MODE 2: C bf16 TRANSPOSED: Ct[col * ldt + row]  (ldt = M stride).
// M%128==0, K%32==0; N guarded on store; B readable up to ceil(N/128)*128 rows.
// ---------------------------------------------------------------------------
template <int MODE>
__global__ __launch_bounds__(256) void gemm_bf16_nt(const unsigned short* __restrict__ A,
                                                    const unsigned short* __restrict__ Bm,
                                                    void* __restrict__ Cv,
                                                    int M, int N, int K, int ldt) {
    __shared__ unsigned short As[128 * 32];
    __shared__ unsigned short Bs[128 * 32];
    const int tid = threadIdx.x;
    const int m0 = blockIdx.y * 128;
    const int n0 = blockIdx.x * 128;
    const int wave = tid >> 6, lane = tid & 63;
    const int wm = (wave & 1) * 64, wn = (wave >> 1) * 64;
    const int fr = lane & 15;
    const int fk = (lane >> 4) * 8;

    f32x4 acc[4][4];
#pragma unroll
    for (int i = 0; i < 4; ++i)
#pragma unroll
        for (int j = 0; j < 4; ++j) acc[i][j] = (f32x4)0.f;

    const int c0 = tid, c1 = tid + 256;
    const int r0 = c0 >> 2, q0 = (c0 & 3) * 8;
    const int r1 = c1 >> 2, q1 = (c1 & 3) * 8;

    for (int k0 = 0; k0 < K; k0 += 32) {
        __builtin_amdgcn_global_load_lds(
            (const __attribute__((address_space(1))) void*)(A + (size_t)(m0 + r0) * K + k0 + q0),
            (__attribute__((address_space(3))) void*)(As + c0 * 8), 16, 0, 0);
        __builtin_amdgcn_global_load_lds(
            (const __attribute__((address_space(1))) void*)(A + (size_t)(m0 + r1) * K + k0 + q1),
            (__attribute__((address_space(3))) void*)(As + c1 * 8), 16, 0, 0);
        __builtin_amdgcn_global_load_lds(
            (const __attribute__((address_space(1))) void*)(Bm + (size_t)(n0 + r0) * K + k0 + q0),
            (__attribute__((address_space(3))) void*)(Bs + c0 * 8), 16, 0, 0);
        __builtin_amdgcn_global_load_lds(
            (const __attribute__((address_space(1))) void*)(Bm + (size_t)(n0 + r1) * K + k0 + q1),
            (__attribute__((address_space(3))) void*)(Bs + c1 * 8), 16, 0, 0);
        __syncthreads();

        bf16x8 af[4], bfr[4];
#pragma unroll
        for (int mb = 0; mb < 4; ++mb)
            af[mb] = *(const bf16x8*)(As + (wm + mb * 16 + fr) * 32 + fk);
#pragma unroll
        for (int nb = 0; nb < 4; ++nb)
            bfr[nb] = *(const bf16x8*)(Bs + (wn + nb * 16 + fr) * 32 + fk);
#pragma unroll
        for (int mb = 0; mb < 4; ++mb)
#pragma unroll
            for (int nb = 0; nb < 4; ++nb)
                acc[mb][nb] = __builtin_amdgcn_mfma_f32_16x16x32_bf16(
                    af[mb], bfr[nb], acc[mb][nb], 0, 0, 0);
        __syncthreads();
    }

    const int orow = (lane >> 4) * 4;
#pragma unroll
    for (int nb = 0; nb < 4; ++nb) {
        const int col = n0 + wn + nb * 16 + fr;
        if (col < N) {
#pragma unroll
            for (int mb = 0; mb < 4; ++mb) {
                const int row = m0 + wm + mb * 16 + orow;
                if (MODE == 0) {
                    float* C = (float*)Cv;
#pragma unroll
                    for (int r = 0; r < 4; ++r)
                        C[(size_t)(row + r) * N + col] = acc[mb][nb][r];
                } else if (MODE == 1) {
                    unsigned short* C = (unsigned short*)Cv;
#pragma unroll
                    for (int r = 0; r < 4; ++r)
                        C[(size_t)(row + r) * N + col] = f2bf(acc[mb][nb][r]);
                } else {
                    unsigned short* C = (unsigned short*)Cv;
                    f32x4 a = acc[mb][nb];
                    *(ushort4*)&C[(size_t)col * ldt + row] =
                        make_ushort4(f2bf(a[0]), f2bf(a[1]), f2bf(a[2]), f2bf(a[3]));
                }
            }
        }
    }
}

// ---------------------------------------------------------------------------
// MFMA causal Taylor linear attention.
//   S^T = K Q^T  (so C-layout stores contiguously into row-major ss[i][j])
//   poly: S = 1 + a/4 + a^2/32, causal mask on diag tile, den += rowsum
//   O^T = V^T S^T (V^T fragments direct from global vt[c][bt]; S^T B-frags
//   are row-major b128 reads of ss)
// Block = (qt, h, bi), 4 waves. Double-buffered ss -> 1 barrier/iter.
// ---------------------------------------------------------------------------
__global__ __launch_bounds__(256) void based_attn_mfma(const unsigned short* __restrict__ qb,
                                                       const unsigned short* __restrict__ kb,
                                                       const unsigned short* __restrict__ vt,
                                                       unsigned short* __restrict__ yb) {
    const int qt = (T / 64 - 1) - blockIdx.x;   // heavy blocks first
    const int h  = blockIdx.y;
    const int bi = blockIdx.z;
    const int tid = threadIdx.x;
    const int wave = tid >> 6, lane = tid & 63;
    const int fr = lane & 15, quad = lane >> 4;
    const int fk = quad * 8;

    __shared__ __attribute__((aligned(16))) unsigned short ss[2][64][72];
    __shared__ float den_lds[64];
    if (tid < 64) den_lds[tid] = 0.f;

    const bf16x8 zf = {};
    // persistent Q B-frags: B[k][n] = Q[n=i][k], i = nt*16 + fr, k=fk (pad>=16 -> 0)
    bf16x8 qf[4];
#pragma unroll
    for (int nt = 0; nt < 4; ++nt) {
        qf[nt] = zf;
        if (quad < 2)
            qf[nt] = *(const bf16x8*)&qb[(size_t)(bi * T + qt * 64 + nt * 16 + fr) * (NH * DK)
                                         + h * DK + fk];
    }

    f32x4 oacc[2][4];
#pragma unroll
    for (int mt = 0; mt < 2; ++mt)
#pragma unroll
        for (int nt = 0; nt < 4; ++nt) oacc[mt][nt] = (f32x4)0.f;
    float denp[4] = {0.f, 0.f, 0.f, 0.f};

    for (int kt = 0; kt <= qt; ++kt) {
        const int bsel = kt & 1;
        // K A-frag: A[m=j][k], j = wave*16 + fr
        bf16x8 kf = zf;
        if (quad < 2)
            kf = *(const bf16x8*)&kb[(size_t)(bi * T + kt * 64 + wave * 16 + fr) * (NH * DK)
                                     + h * DK + fk];
        // V^T A-frags (prefetch): A[m=c][k=s], c = wave*32 + mt*16 + fr
        bf16x8 vf[2][2];
#pragma unroll
        for (int mt = 0; mt < 2; ++mt)
#pragma unroll
            for (int k2 = 0; k2 < 2; ++k2)
                vf[mt][k2] = *(const bf16x8*)&vt[(size_t)(h * DV + wave * 32 + mt * 16 + fr) * BT
                                                 + bi * T + kt * 64 + k2 * 32 + fk];
        // S^T: wave owns j-strip [wave*16, wave*16+16)
        f32x4 sa[4];
#pragma unroll
        for (int nt = 0; nt < 4; ++nt)
            sa[nt] = __builtin_amdgcn_mfma_f32_16x16x32_bf16(kf, qf[nt], (f32x4)0.f, 0, 0, 0);

        const bool diag = (kt == qt);
#pragma unroll
        for (int nt = 0; nt < 4; ++nt) {
            const int i = nt * 16 + fr;
            float sv[4];
#pragma unroll
            for (int r = 0; r < 4; ++r) {
                const int j = wave * 16 + quad * 4 + r;
                const float a = sa[nt][r];
                float s = 1.f + 0.25f * a + a * a * (1.f / 32.f);
                if (diag && (j > i)) s = 0.f;
                sv[r] = s;
                denp[nt] += s;
            }
            *(ushort4*)&ss[bsel][i][wave * 16 + quad * 4] =
                make_ushort4(f2bf(sv[0]), f2bf(sv[1]), f2bf(sv[2]), f2bf(sv[3]));
        }
        __syncthreads();

        // O^T += V^T S^T : wave owns c-chunk [wave*32, wave*32+32)
#pragma unroll
        for (int k2 = 0; k2 < 2; ++k2) {
            bf16x8 sf[4];
#pragma unroll
            for (int nt = 0; nt < 4; ++nt)
                sf[nt] = *(const bf16x8*)&ss[bsel][nt * 16 + fr][k2 * 32 + fk];
#pragma unroll
            for (int mt = 0; mt < 2; ++mt)
#pragma unroll
                for (int nt = 0; nt < 4; ++nt)
                    oacc[mt][nt] = __builtin_amdgcn_mfma_f32_16x16x32_bf16(
                        vf[mt][k2], sf[nt], oacc[mt][nt], 0, 0, 0);
        }
    }

    // den: reduce across quads (same fr), then across waves via LDS atomics
#pragma unroll
    for (int nt = 0; nt < 4; ++nt) {
        float v = denp[nt];
        v += __shfl_xor(v, 16);
        v += __shfl_xor(v, 32);
        if (quad == 0) atomicAdd(&den_lds[nt * 16 + fr], v);
    }
    __syncthreads();

    // y[i][c] = O^T[c][i] / den[i], bf16 row-major [bt][1536]
#pragma unroll
    for (int nt = 0; nt < 4; ++nt) {
        const int i = nt * 16 + fr;
        const float rd = 1.f / (den_lds[i] + EPS);
        const size_t rowbase = (size_t)(bi * T + qt * 64 + i) * (NH * DV) + h * DV;
#pragma unroll
        for (int mt = 0; mt < 2; ++mt) {
            const int c = wave * 32 + mt * 16 + quad * 4;
            const f32x4 o = oacc[mt][nt];
            *(ushort4*)&yb[rowbase + c] = make_ushort4(f2bf(o[0] * rd), f2bf(o[1] * rd),
                                                       f2bf(o[2] * rd), f2bf(o[3] * rd));
        }
    }
}

extern "C" void kernel_launch(void* const* d_in, const int* in_sizes, int n_in,
                              void* d_out, int out_size, void* d_ws, size_t ws_size,
                              hipStream_t stream) {
    (void)in_sizes; (void)n_in; (void)out_size; (void)ws_size;
    const float* hs = (const float*)d_in[0];
    const float* Wq = (const float*)d_in[1];
    const float* Wk = (const float*)d_in[2];
    const float* Wv = (const float*)d_in[3];
    const float* Wo = (const float*)d_in[4];
    float* out = (float*)d_out;

    // bf16 workspace layout (~51.9 MB)
    unsigned short* hsb = (unsigned short*)d_ws;        // [BT][HID]
    unsigned short* wqb = hsb + (size_t)BT * HID;       // [256][HID] (rows 192.. pad-read ok)
    unsigned short* wkb = wqb + (size_t)256 * HID;
    unsigned short* wvb = wkb + (size_t)256 * HID;      // [HID][HID]
    unsigned short* wob = wvb + (size_t)HID * HID;
    unsigned short* qkq = wob + (size_t)HID * HID;      // [BT][192]
    unsigned short* qkk = qkq + (size_t)BT * NH * DK;
    unsigned short* vtg = qkk + (size_t)BT * NH * DK;   // [HID][BT] transposed
    unsigned short* ybb = vtg + (size_t)HID * BT;       // [BT][HID]

    dim3 blk(256);
    cvt_bf16<<<dim3(BT * HID / 8 / 256), blk, 0, stream>>>(hs, hsb, BT * HID);
    cvt_bf16<<<dim3(NH * DK * HID / 8 / 256), blk, 0, stream>>>(Wq, wqb, NH * DK * HID);
    cvt_bf16<<<dim3(NH * DK * HID / 8 / 256), blk, 0, stream>>>(Wk, wkb, NH * DK * HID);
    cvt_bf16<<<dim3(HID * HID / 8 / 256), blk, 0, stream>>>(Wv, wvb, HID * HID);
    cvt_bf16<<<dim3(HID * HID / 8 / 256), blk, 0, stream>>>(Wo, wob, HID * HID);

    // projections
    gemm_bf16_nt<1><<<dim3(2, 32), blk, 0, stream>>>(hsb, wqb, qkq, BT, NH * DK, HID, 0);
    gemm_bf16_nt<1><<<dim3(2, 32), blk, 0, stream>>>(hsb, wkb, qkk, BT, NH * DK, HID, 0);
    gemm_bf16_nt<2><<<dim3(12, 32), blk, 0, stream>>>(hsb, wvb, vtg, BT, NH * DV, HID, BT);

    // attention
    based_attn_mfma<<<dim3(T / 64, NH, B), blk, 0, stream>>>(qkq, qkk, vtg, ybb);

    // output projection (fp32 out)
    gemm_bf16_nt<0><<<dim3(12, 32), blk, 0, stream>>>(ybb, wob, out, BT, HID, HID, 0);
}

// Round 5
// 256.070 us; speedup vs baseline: 6.7833x; 1.2235x over previous
//
#include <hip/hip_runtime.h>

#define B 2
#define T 2048
#define HID 1536
#define NH 12
#define DK 16
#define DV 128
#define BT (B * T)
#define EPS 1e-12f

typedef __attribute__((ext_vector_type(8))) short bf16x8;
typedef __attribute__((ext_vector_type(4))) float f32x4;

__device__ __forceinline__ unsigned short f2bf(float f) {
    unsigned int u = __float_as_uint(f);
    u += 0x7FFFu + ((u >> 16) & 1u);
    return (unsigned short)(u >> 16);
}

// ---------------------------------------------------------------------------
// Fused fp32->bf16 for all 5 inputs. Segments in 2048-element blocks:
// hs 3072 | Wq 144 | Wk 144 | Wv 1152 | Wo 1152 = 5664 blocks.
// Wq+Wk land concatenated in wqk [384][1536].
// ---------------------------------------------------------------------------
__global__ __launch_bounds__(256) void cvt_all(const float* __restrict__ hs,
                                               const float* __restrict__ Wq,
                                               const float* __restrict__ Wk,
                                               const float* __restrict__ Wv,
                                               const float* __restrict__ Wo,
                                               unsigned short* __restrict__ hsb,
                                               unsigned short* __restrict__ wqk,
                                               unsigned short* __restrict__ wvb,
                                               unsigned short* __restrict__ wob) {
    int bx = blockIdx.x;
    const float* src;
    unsigned short* dst;
    if (bx < 3072)      { src = hs; dst = hsb; }
    else if (bx < 3216) { src = Wq; dst = wqk;          bx -= 3072; }
    else if (bx < 3360) { src = Wk; dst = wqk + 294912; bx -= 3216; }
    else if (bx < 4512) { src = Wv; dst = wvb;          bx -= 3360; }
    else                { src = Wo; dst = wob;          bx -= 4512; }
    const int i = (bx * 256 + threadIdx.x) * 8;
    float4 a = *(const float4*)(src + i);
    float4 b = *(const float4*)(src + i + 4);
    *(ushort4*)(dst + i)     = make_ushort4(f2bf(a.x), f2bf(a.y), f2bf(a.z), f2bf(a.w));
    *(ushort4*)(dst + i + 4) = make_ushort4(f2bf(b.x), f2bf(b.y), f2bf(b.z), f2bf(b.w));
}

// ---------------------------------------------------------------------------
// C[M,N] = A[M,K] @ B[N,K]^T, A/B bf16.  m97 structure: 128x128 tile, BK=32,
// global_load_lds width=16, 16x16x32 bf16 MFMA, 4 waves x 4x4 frags.
// MODE 0: C fp32 row-major.  MODE 1: C bf16 row-major.
// M%128==0, N%128==0, K%32==0.
// ---------------------------------------------------------------------------
template <int MODE>
__global__ __launch_bounds__(256) void gemm_bf16_nt(const unsigned short* __restrict__ A,
                                                    const unsigned short* __restrict__ Bm,
                                                    void* __restrict__ Cv,
                                                    int M, int N, int K) {
    __shared__ unsigned short As[128 * 32];
    __shared__ unsigned short Bs[128 * 32];
    const int tid = threadIdx.x;
    const int m0 = blockIdx.y * 128;
    const int n0 = blockIdx.x * 128;
    const int wave = tid >> 6, lane = tid & 63;
    const int wm = (wave & 1) * 64, wn = (wave >> 1) * 64;
    const int fr = lane & 15;
    const int fk = (lane >> 4) * 8;

    f32x4 acc[4][4];
#pragma unroll
    for (int i = 0; i < 4; ++i)
#pragma unroll
        for (int j = 0; j < 4; ++j) acc[i][j] = (f32x4)0.f;

    const int c0 = tid, c1 = tid + 256;
    const int r0 = c0 >> 2, q0 = (c0 & 3) * 8;
    const int r1 = c1 >> 2, q1 = (c1 & 3) * 8;

    for (int k0 = 0; k0 < K; k0 += 32) {
        __builtin_amdgcn_global_load_lds(
            (const __attribute__((address_space(1))) void*)(A + (size_t)(m0 + r0) * K + k0 + q0),
            (__attribute__((address_space(3))) void*)(As + c0 * 8), 16, 0, 0);
        __builtin_amdgcn_global_load_lds(
            (const __attribute__((address_space(1))) void*)(A + (size_t)(m0 + r1) * K + k0 + q1),
            (__attribute__((address_space(3))) void*)(As + c1 * 8), 16, 0, 0);
        __builtin_amdgcn_global_load_lds(
            (const __attribute__((address_space(1))) void*)(Bm + (size_t)(n0 + r0) * K + k0 + q0),
            (__attribute__((address_space(3))) void*)(Bs + c0 * 8), 16, 0, 0);
        __builtin_amdgcn_global_load_lds(
            (const __attribute__((address_space(1))) void*)(Bm + (size_t)(n0 + r1) * K + k0 + q1),
            (__attribute__((address_space(3))) void*)(Bs + c1 * 8), 16, 0, 0);
        __syncthreads();

        bf16x8 af[4], bfr[4];
#pragma unroll
        for (int mb = 0; mb < 4; ++mb)
            af[mb] = *(const bf16x8*)(As + (wm + mb * 16 + fr) * 32 + fk);
#pragma unroll
        for (int nb = 0; nb < 4; ++nb)
            bfr[nb] = *(const bf16x8*)(Bs + (wn + nb * 16 + fr) * 32 + fk);
#pragma unroll
        for (int mb = 0; mb < 4; ++mb)
#pragma unroll
            for (int nb = 0; nb < 4; ++nb)
                acc[mb][nb] = __builtin_amdgcn_mfma_f32_16x16x32_bf16(
                    af[mb], bfr[nb], acc[mb][nb], 0, 0, 0);
        __syncthreads();
    }

    const int orow = (lane >> 4) * 4;
#pragma unroll
    for (int nb = 0; nb < 4; ++nb) {
        const int col = n0 + wn + nb * 16 + fr;
#pragma unroll
        for (int mb = 0; mb < 4; ++mb) {
            const int row = m0 + wm + mb * 16 + orow;
            if (MODE == 0) {
                float* C = (float*)Cv;
#pragma unroll
                for (int r = 0; r < 4; ++r)
                    C[(size_t)(row + r) * N + col] = acc[mb][nb][r];
            } else {
                unsigned short* C = (unsigned short*)Cv;
#pragma unroll
                for (int r = 0; r < 4; ++r)
                    C[(size_t)(row + r) * N + col] = f2bf(acc[mb][nb][r]);
            }
        }
    }
}

// ---------------------------------------------------------------------------
// MFMA causal Taylor linear attention (collapsed features).
//   S^T = K Q^T ; S = 1 + a/4 + a^2/32, causal mask on diag tile
//   O^T = V^T S^T ; y = O^T/den
// qk: [BT][384] bf16 (q cols 0..191, k cols 192..383); vt: [HID][BT] bf16.
// 1D grid, qt-major heavy-first: 24 heaviest blocks dispatch first.
// ---------------------------------------------------------------------------
__global__ __launch_bounds__(256) void based_attn_mfma(const unsigned short* __restrict__ qk,
                                                       const unsigned short* __restrict__ vt,
                                                       unsigned short* __restrict__ yb) {
    const int bx = blockIdx.x;
    const int qt = (T / 64 - 1) - (bx / (NH * B));
    const int hb = bx % (NH * B);
    const int h  = hb >> 1;
    const int bi = hb & 1;
    const int tid = threadIdx.x;
    const int wave = tid >> 6, lane = tid & 63;
    const int fr = lane & 15, quad = lane >> 4;
    const int fk = quad * 8;

    __shared__ __attribute__((aligned(16))) unsigned short ss[2][64][72];
    __shared__ float den_lds[64];
    if (tid < 64) den_lds[tid] = 0.f;

    const bf16x8 zf = {};
    // persistent Q B-frags: B[k][n] = Q[n=i][k], i = nt*16+fr (k pad>=16 -> 0)
    bf16x8 qf[4];
#pragma unroll
    for (int nt = 0; nt < 4; ++nt) {
        qf[nt] = zf;
        if (quad < 2)
            qf[nt] = *(const bf16x8*)&qk[(size_t)(bi * T + qt * 64 + nt * 16 + fr) * 384
                                         + h * DK + fk];
    }

    f32x4 oacc[2][4];
#pragma unroll
    for (int mt = 0; mt < 2; ++mt)
#pragma unroll
        for (int nt = 0; nt < 4; ++nt) oacc[mt][nt] = (f32x4)0.f;
    float denp[4] = {0.f, 0.f, 0.f, 0.f};

    for (int kt = 0; kt <= qt; ++kt) {
        const int bsel = kt & 1;
        // K A-frag: A[m=j][k], j = wave*16 + fr
        bf16x8 kf = zf;
        if (quad < 2)
            kf = *(const bf16x8*)&qk[(size_t)(bi * T + kt * 64 + wave * 16 + fr) * 384
                                     + 192 + h * DK + fk];
        // V^T A-frags: A[m=c][k=s], c = wave*32 + mt*16 + fr
        bf16x8 vf[2][2];
#pragma unroll
        for (int mt = 0; mt < 2; ++mt)
#pragma unroll
            for (int k2 = 0; k2 < 2; ++k2)
                vf[mt][k2] = *(const bf16x8*)&vt[(size_t)(h * DV + wave * 32 + mt * 16 + fr) * BT
                                                 + bi * T + kt * 64 + k2 * 32 + fk];
        // S^T: wave owns j-strip [wave*16, wave*16+16)
        f32x4 sa[4];
#pragma unroll
        for (int nt = 0; nt < 4; ++nt)
            sa[nt] = __builtin_amdgcn_mfma_f32_16x16x32_bf16(kf, qf[nt], (f32x4)0.f, 0, 0, 0);

        const bool diag = (kt == qt);
#pragma unroll
        for (int nt = 0; nt < 4; ++nt) {
            const int i = nt * 16 + fr;
            float sv[4];
#pragma unroll
            for (int r = 0; r < 4; ++r) {
                const int j = wave * 16 + quad * 4 + r;
                const float a = sa[nt][r];
                float s = 1.f + 0.25f * a + a * a * (1.f / 32.f);
                if (diag && (j > i)) s = 0.f;
                sv[r] = s;
                denp[nt] += s;
            }
            *(ushort4*)&ss[bsel][i][wave * 16 + quad * 4] =
                make_ushort4(f2bf(sv[0]), f2bf(sv[1]), f2bf(sv[2]), f2bf(sv[3]));
        }
        __syncthreads();

        // O^T += V^T S^T : wave owns c-chunk [wave*32, wave*32+32)
#pragma unroll
        for (int k2 = 0; k2 < 2; ++k2) {
            bf16x8 sf[4];
#pragma unroll
            for (int nt = 0; nt < 4; ++nt)
                sf[nt] = *(const bf16x8*)&ss[bsel][nt * 16 + fr][k2 * 32 + fk];
#pragma unroll
            for (int mt = 0; mt < 2; ++mt)
#pragma unroll
                for (int nt = 0; nt < 4; ++nt)
                    oacc[mt][nt] = __builtin_amdgcn_mfma_f32_16x16x32_bf16(
                        vf[mt][k2], sf[nt], oacc[mt][nt], 0, 0, 0);
        }
    }

    // den: quad-reduce (same fr), then cross-wave via LDS atomics
#pragma unroll
    for (int nt = 0; nt < 4; ++nt) {
        float v = denp[nt];
        v += __shfl_xor(v, 16);
        v += __shfl_xor(v, 32);
        if (quad == 0) atomicAdd(&den_lds[nt * 16 + fr], v);
    }
    __syncthreads();

    // y[i][c] = O^T[c][i] / den[i], bf16 row-major [BT][HID]
#pragma unroll
    for (int nt = 0; nt < 4; ++nt) {
        const int i = nt * 16 + fr;
        const float rd = 1.f / (den_lds[i] + EPS);
        const size_t rowbase = (size_t)(bi * T + qt * 64 + i) * (NH * DV) + h * DV;
#pragma unroll
        for (int mt = 0; mt < 2; ++mt) {
            const int c = wave * 32 + mt * 16 + quad * 4;
            const f32x4 o = oacc[mt][nt];
            *(ushort4*)&yb[rowbase + c] = make_ushort4(f2bf(o[0] * rd), f2bf(o[1] * rd),
                                                       f2bf(o[2] * rd), f2bf(o[3] * rd));
        }
    }
}

extern "C" void kernel_launch(void* const* d_in, const int* in_sizes, int n_in,
                              void* d_out, int out_size, void* d_ws, size_t ws_size,
                              hipStream_t stream) {
    (void)in_sizes; (void)n_in; (void)out_size; (void)ws_size;
    const float* hs = (const float*)d_in[0];
    const float* Wq = (const float*)d_in[1];
    const float* Wk = (const float*)d_in[2];
    const float* Wv = (const float*)d_in[3];
    const float* Wo = (const float*)d_in[4];
    float* out = (float*)d_out;

    // bf16 workspace (~51.5 MB)
    unsigned short* hsb = (unsigned short*)d_ws;        // [BT][HID]
    unsigned short* wqk = hsb + (size_t)BT * HID;       // [384][HID]  (Wq ; Wk)
    unsigned short* wvb = wqk + (size_t)384 * HID;      // [HID][HID]
    unsigned short* wob = wvb + (size_t)HID * HID;      // [HID][HID]
    unsigned short* qkb = wob + (size_t)HID * HID;      // [BT][384]
    unsigned short* vtg = qkb + (size_t)BT * 384;       // [HID][BT]  (V^T)
    unsigned short* ybb = vtg + (size_t)HID * BT;       // [BT][HID]

    dim3 blk(256);
    cvt_all<<<dim3(5664), blk, 0, stream>>>(hs, Wq, Wk, Wv, Wo, hsb, wqk, wvb, wob);

    // fused Q/K projection: qk[t][0..191]=q, [192..383]=k
    gemm_bf16_nt<1><<<dim3(3, 32), blk, 0, stream>>>(hsb, wqk, qkb, BT, 384, HID);
    // V^T directly row-major: Vt[c][t] = Wv[c][:] . hs[t][:]
    gemm_bf16_nt<1><<<dim3(32, 12), blk, 0, stream>>>(wvb, hsb, vtg, HID, BT, HID);

    based_attn_mfma<<<dim3(T / 64 * NH * B), blk, 0, stream>>>(qkb, vtg, ybb);

    // output projection (fp32 out)
    gemm_bf16_nt<0><<<dim3(12, 32), blk, 0, stream>>>(ybb, wob, out, BT, HID, HID);
}

// Round 6
// 216.422 us; speedup vs baseline: 8.0259x; 1.1832x over previous
//
#include <hip/hip_runtime.h>

#define B 2
#define T 2048
#define HID 1536
#define NH 12
#define DK 16
#define DV 128
#define BT (B * T)
#define EPS 1e-12f

typedef __attribute__((ext_vector_type(8))) short bf16x8;
typedef __attribute__((ext_vector_type(4))) float f32x4;

__device__ __forceinline__ unsigned short f2bf(float f) {
    unsigned int u = __float_as_uint(f);
    u += 0x7FFFu + ((u >> 16) & 1u);
    return (unsigned short)(u >> 16);
}

// ---------------------------------------------------------------------------
// Fused fp32->bf16 for all 5 inputs. Segments in 2048-element blocks:
// hs 3072 | Wq 144 | Wk 144 | Wv 1152 | Wo 1152 = 5664 blocks.
// Wq+Wk land concatenated in wqk [384][1536].
// ---------------------------------------------------------------------------
__global__ __launch_bounds__(256) void cvt_all(const float* __restrict__ hs,
                                               const float* __restrict__ Wq,
                                               const float* __restrict__ Wk,
                                               const float* __restrict__ Wv,
                                               const float* __restrict__ Wo,
                                               unsigned short* __restrict__ hsb,
                                               unsigned short* __restrict__ wqk,
                                               unsigned short* __restrict__ wvb,
                                               unsigned short* __restrict__ wob) {
    int bx = blockIdx.x;
    const float* src;
    unsigned short* dst;
    if (bx < 3072)      { src = hs; dst = hsb; }
    else if (bx < 3216) { src = Wq; dst = wqk;          bx -= 3072; }
    else if (bx < 3360) { src = Wk; dst = wqk + 294912; bx -= 3216; }
    else if (bx < 4512) { src = Wv; dst = wvb;          bx -= 3360; }
    else                { src = Wo; dst = wob;          bx -= 4512; }
    const int i = (bx * 256 + threadIdx.x) * 8;
    float4 a = *(const float4*)(src + i);
    float4 b = *(const float4*)(src + i + 4);
    *(ushort4*)(dst + i)     = make_ushort4(f2bf(a.x), f2bf(a.y), f2bf(a.z), f2bf(a.w));
    *(ushort4*)(dst + i + 4) = make_ushort4(f2bf(b.x), f2bf(b.y), f2bf(b.z), f2bf(b.w));
}

// ---------------------------------------------------------------------------
// Generic m97-style 128x128 bf16 GEMM tile body (BK=32, global_load_lds w=16,
// 16x16x32 MFMA, 4 waves x 4x4 frags). C bf16 row-major, no store guards
// (M,N multiples of 128). Inlined by both GEMM kernels below.
// ---------------------------------------------------------------------------
__device__ __forceinline__ void gemm_tile_bf16(const unsigned short* __restrict__ A,
                                               const unsigned short* __restrict__ Bm,
                                               unsigned short* __restrict__ C,
                                               int m0, int n0, int K, int ldc,
                                               unsigned short* As, unsigned short* Bs) {
    const int tid = threadIdx.x;
    const int wave = tid >> 6, lane = tid & 63;
    const int wm = (wave & 1) * 64, wn = (wave >> 1) * 64;
    const int fr = lane & 15;
    const int fk = (lane >> 4) * 8;

    f32x4 acc[4][4];
#pragma unroll
    for (int i = 0; i < 4; ++i)
#pragma unroll
        for (int j = 0; j < 4; ++j) acc[i][j] = (f32x4)0.f;

    const int c0 = tid, c1 = tid + 256;
    const int r0 = c0 >> 2, q0 = (c0 & 3) * 8;
    const int r1 = c1 >> 2, q1 = (c1 & 3) * 8;

    for (int k0 = 0; k0 < K; k0 += 32) {
        __builtin_amdgcn_global_load_lds(
            (const __attribute__((address_space(1))) void*)(A + (size_t)(m0 + r0) * K + k0 + q0),
            (__attribute__((address_space(3))) void*)(As + c0 * 8), 16, 0, 0);
        __builtin_amdgcn_global_load_lds(
            (const __attribute__((address_space(1))) void*)(A + (size_t)(m0 + r1) * K + k0 + q1),
            (__attribute__((address_space(3))) void*)(As + c1 * 8), 16, 0, 0);
        __builtin_amdgcn_global_load_lds(
            (const __attribute__((address_space(1))) void*)(Bm + (size_t)(n0 + r0) * K + k0 + q0),
            (__attribute__((address_space(3))) void*)(Bs + c0 * 8), 16, 0, 0);
        __builtin_amdgcn_global_load_lds(
            (const __attribute__((address_space(1))) void*)(Bm + (size_t)(n0 + r1) * K + k0 + q1),
            (__attribute__((address_space(3))) void*)(Bs + c1 * 8), 16, 0, 0);
        __syncthreads();

        bf16x8 af[4], bfr[4];
#pragma unroll
        for (int mb = 0; mb < 4; ++mb)
            af[mb] = *(const bf16x8*)(As + (wm + mb * 16 + fr) * 32 + fk);
#pragma unroll
        for (int nb = 0; nb < 4; ++nb)
            bfr[nb] = *(const bf16x8*)(Bs + (wn + nb * 16 + fr) * 32 + fk);
#pragma unroll
        for (int mb = 0; mb < 4; ++mb)
#pragma unroll
            for (int nb = 0; nb < 4; ++nb)
                acc[mb][nb] = __builtin_amdgcn_mfma_f32_16x16x32_bf16(
                    af[mb], bfr[nb], acc[mb][nb], 0, 0, 0);
        __syncthreads();
    }

    const int orow = (lane >> 4) * 4;
#pragma unroll
    for (int nb = 0; nb < 4; ++nb) {
        const int col = n0 + wn + nb * 16 + fr;
#pragma unroll
        for (int mb = 0; mb < 4; ++mb) {
            const int row = m0 + wm + mb * 16 + orow;
#pragma unroll
            for (int r = 0; r < 4; ++r)
                C[(size_t)(row + r) * ldc + col] = f2bf(acc[mb][nb][r]);
        }
    }
}

// ---------------------------------------------------------------------------
// Fused QK-proj + V^T-proj, one launch, 480 blocks:
//   bx <  96: qk[BT][384] = hsb @ wqk^T           (m-tile bx/3, n-tile bx%3)
//   bx >= 96: vt[HID][BT] = wvb @ hsb^T (V^T)      (4-wide n-supertile swizzle)
// ---------------------------------------------------------------------------
__global__ __launch_bounds__(256) void proj_qkv(const unsigned short* __restrict__ hsb,
                                                const unsigned short* __restrict__ wqk,
                                                const unsigned short* __restrict__ wvb,
                                                unsigned short* __restrict__ qkb,
                                                unsigned short* __restrict__ vtg) {
    __shared__ unsigned short As[128 * 32];
    __shared__ unsigned short Bs[128 * 32];
    const int bx = blockIdx.x;
    if (bx < 96) {
        gemm_tile_bf16(hsb, wqk, qkb, (bx / 3) * 128, (bx % 3) * 128, HID, 384, As, Bs);
    } else {
        const int vid = bx - 96;
        const int grp = vid / 48, sub = vid % 48;
        const int n_t = grp * 4 + (sub & 3), m_t = sub >> 2;
        gemm_tile_bf16(wvb, hsb, vtg, m_t * 128, n_t * 128, HID, BT, As, Bs);
    }
}

// ---------------------------------------------------------------------------
// Output projection: out[BT][HID] fp32 = ybb @ wob^T.
// ---------------------------------------------------------------------------
__global__ __launch_bounds__(256) void proj_out(const unsigned short* __restrict__ A,
                                                const unsigned short* __restrict__ Bm,
                                                float* __restrict__ C) {
    __shared__ unsigned short As[128 * 32];
    __shared__ unsigned short Bs[128 * 32];
    const int tid = threadIdx.x;
    const int m0 = blockIdx.y * 128;
    const int n0 = blockIdx.x * 128;
    const int wave = tid >> 6, lane = tid & 63;
    const int wm = (wave & 1) * 64, wn = (wave >> 1) * 64;
    const int fr = lane & 15;
    const int fk = (lane >> 4) * 8;
    const int K = HID;

    f32x4 acc[4][4];
#pragma unroll
    for (int i = 0; i < 4; ++i)
#pragma unroll
        for (int j = 0; j < 4; ++j) acc[i][j] = (f32x4)0.f;

    const int c0 = tid, c1 = tid + 256;
    const int r0 = c0 >> 2, q0 = (c0 & 3) * 8;
    const int r1 = c1 >> 2, q1 = (c1 & 3) * 8;

    for (int k0 = 0; k0 < K; k0 += 32) {
        __builtin_amdgcn_global_load_lds(
            (const __attribute__((address_space(1))) void*)(A + (size_t)(m0 + r0) * K + k0 + q0),
            (__attribute__((address_space(3))) void*)(As + c0 * 8), 16, 0, 0);
        __builtin_amdgcn_global_load_lds(
            (const __attribute__((address_space(1))) void*)(A + (size_t)(m0 + r1) * K + k0 + q1),
            (__attribute__((address_space(3))) void*)(As + c1 * 8), 16, 0, 0);
        __builtin_amdgcn_global_load_lds(
            (const __attribute__((address_space(1))) void*)(Bm + (size_t)(n0 + r0) * K + k0 + q0),
            (__attribute__((address_space(3))) void*)(Bs + c0 * 8), 16, 0, 0);
        __builtin_amdgcn_global_load_lds(
            (const __attribute__((address_space(1))) void*)(Bm + (size_t)(n0 + r1) * K + k0 + q1),
            (__attribute__((address_space(3))) void*)(Bs + c1 * 8), 16, 0, 0);
        __syncthreads();

        bf16x8 af[4], bfr[4];
#pragma unroll
        for (int mb = 0; mb < 4; ++mb)
            af[mb] = *(const bf16x8*)(As + (wm + mb * 16 + fr) * 32 + fk);
#pragma unroll
        for (int nb = 0; nb < 4; ++nb)
            bfr[nb] = *(const bf16x8*)(Bs + (wn + nb * 16 + fr) * 32 + fk);
#pragma unroll
        for (int mb = 0; mb < 4; ++mb)
#pragma unroll
            for (int nb = 0; nb < 4; ++nb)
                acc[mb][nb] = __builtin_amdgcn_mfma_f32_16x16x32_bf16(
                    af[mb], bfr[nb], acc[mb][nb], 0, 0, 0);
        __syncthreads();
    }

    const int orow = (lane >> 4) * 4;
#pragma unroll
    for (int nb = 0; nb < 4; ++nb) {
        const int col = n0 + wn + nb * 16 + fr;
#pragma unroll
        for (int mb = 0; mb < 4; ++mb) {
            const int row = m0 + wm + mb * 16 + orow;
#pragma unroll
            for (int r = 0; r < 4; ++r)
                C[(size_t)(row + r) * HID + col] = acc[mb][nb][r];
        }
    }
}

// ---------------------------------------------------------------------------
// MFMA causal Taylor linear attention, dv-split x2 for parallelism.
//   S^T = K Q^T ; S = 1 + a/4 + a^2/32, causal mask on diag tile
//   O^T = V^T S^T ; y = O^T/den
// Block = (qt, h, bi, dvs): computes 64 of the 128 v-channels; S^T + poly
// duplicated across the dvs pair (cheap, buys 2x TLP).
// 1536 blocks, qt-major heavy-first.
// ---------------------------------------------------------------------------
__global__ __launch_bounds__(256) void based_attn_mfma(const unsigned short* __restrict__ qk,
                                                       const unsigned short* __restrict__ vt,
                                                       unsigned short* __restrict__ yb) {
    const int bx = blockIdx.x;
    const int qt = (T / 64 - 1) - (bx / (NH * B * 2));
    const int sub = bx % (NH * B * 2);
    const int h   = sub >> 2;
    const int bi  = (sub >> 1) & 1;
    const int dvs = sub & 1;
    const int tid = threadIdx.x;
    const int wave = tid >> 6, lane = tid & 63;
    const int fr = lane & 15, quad = lane >> 4;
    const int fk = quad * 8;

    __shared__ __attribute__((aligned(16))) unsigned short ss[2][64][72];
    __shared__ float den_lds[64];
    if (tid < 64) den_lds[tid] = 0.f;

    const bf16x8 zf = {};
    // persistent Q B-frags: B[k][n] = Q[n=i][k], i = nt*16+fr (k pad>=16 -> 0)
    bf16x8 qf[4];
#pragma unroll
    for (int nt = 0; nt < 4; ++nt) {
        qf[nt] = zf;
        if (quad < 2)
            qf[nt] = *(const bf16x8*)&qk[(size_t)(bi * T + qt * 64 + nt * 16 + fr) * 384
                                         + h * DK + fk];
    }

    f32x4 oacc[4];
#pragma unroll
    for (int nt = 0; nt < 4; ++nt) oacc[nt] = (f32x4)0.f;
    float denp[4] = {0.f, 0.f, 0.f, 0.f};

    // this block's 16-row V^T slice base for its wave: c = dvs*64 + wave*16 + fr
    const size_t vrow = (size_t)(h * DV + dvs * 64 + wave * 16 + fr) * BT + bi * T;

    for (int kt = 0; kt <= qt; ++kt) {
        const int bsel = kt & 1;
        // K A-frag: A[m=j][k], j = wave*16 + fr
        bf16x8 kf = zf;
        if (quad < 2)
            kf = *(const bf16x8*)&qk[(size_t)(bi * T + kt * 64 + wave * 16 + fr) * 384
                                     + 192 + h * DK + fk];
        // V^T A-frags: A[m=c][k=s]
        bf16x8 vf[2];
#pragma unroll
        for (int k2 = 0; k2 < 2; ++k2)
            vf[k2] = *(const bf16x8*)&vt[vrow + kt * 64 + k2 * 32 + fk];

        // S^T: wave owns j-strip [wave*16, wave*16+16)
        f32x4 sa[4];
#pragma unroll
        for (int nt = 0; nt < 4; ++nt)
            sa[nt] = __builtin_amdgcn_mfma_f32_16x16x32_bf16(kf, qf[nt], (f32x4)0.f, 0, 0, 0);

        const bool diag = (kt == qt);
#pragma unroll
        for (int nt = 0; nt < 4; ++nt) {
            const int i = nt * 16 + fr;
            float sv[4];
#pragma unroll
            for (int r = 0; r < 4; ++r) {
                const int j = wave * 16 + quad * 4 + r;
                const float a = sa[nt][r];
                float s = 1.f + 0.25f * a + a * a * (1.f / 32.f);
                if (diag && (j > i)) s = 0.f;
                sv[r] = s;
                denp[nt] += s;
            }
            *(ushort4*)&ss[bsel][i][wave * 16 + quad * 4] =
                make_ushort4(f2bf(sv[0]), f2bf(sv[1]), f2bf(sv[2]), f2bf(sv[3]));
        }
        __syncthreads();

        // O^T += V^T S^T : wave owns 16-row c-chunk
#pragma unroll
        for (int k2 = 0; k2 < 2; ++k2) {
            bf16x8 sf[4];
#pragma unroll
            for (int nt = 0; nt < 4; ++nt)
                sf[nt] = *(const bf16x8*)&ss[bsel][nt * 16 + fr][k2 * 32 + fk];
#pragma unroll
            for (int nt = 0; nt < 4; ++nt)
                oacc[nt] = __builtin_amdgcn_mfma_f32_16x16x32_bf16(
                    vf[k2], sf[nt], oacc[nt], 0, 0, 0);
        }
    }

    // den: quad-reduce (same fr), then cross-wave via LDS atomics
#pragma unroll
    for (int nt = 0; nt < 4; ++nt) {
        float v = denp[nt];
        v += __shfl_xor(v, 16);
        v += __shfl_xor(v, 32);
        if (quad == 0) atomicAdd(&den_lds[nt * 16 + fr], v);
    }
    __syncthreads();

    // y[i][c] = O^T[c][i] / den[i], bf16 row-major [BT][HID]
#pragma unroll
    for (int nt = 0; nt < 4; ++nt) {
        const int i = nt * 16 + fr;
        const float rd = 1.f / (den_lds[i] + EPS);
        const size_t rowbase = (size_t)(bi * T + qt * 64 + i) * (NH * DV) + h * DV;
        const int c = dvs * 64 + wave * 16 + quad * 4;
        const f32x4 o = oacc[nt];
        *(ushort4*)&yb[rowbase + c] = make_ushort4(f2bf(o[0] * rd), f2bf(o[1] * rd),
                                                   f2bf(o[2] * rd), f2bf(o[3] * rd));
    }
}

extern "C" void kernel_launch(void* const* d_in, const int* in_sizes, int n_in,
                              void* d_out, int out_size, void* d_ws, size_t ws_size,
                              hipStream_t stream) {
    (void)in_sizes; (void)n_in; (void)out_size; (void)ws_size;
    const float* hs = (const float*)d_in[0];
    const float* Wq = (const float*)d_in[1];
    const float* Wk = (const float*)d_in[2];
    const float* Wv = (const float*)d_in[3];
    const float* Wo = (const float*)d_in[4];
    float* out = (float*)d_out;

    // bf16 workspace (~51.5 MB)
    unsigned short* hsb = (unsigned short*)d_ws;        // [BT][HID]
    unsigned short* wqk = hsb + (size_t)BT * HID;       // [384][HID]  (Wq ; Wk)
    unsigned short* wvb = wqk + (size_t)384 * HID;      // [HID][HID]
    unsigned short* wob = wvb + (size_t)HID * HID;      // [HID][HID]
    unsigned short* qkb = wob + (size_t)HID * HID;      // [BT][384]
    unsigned short* vtg = qkb + (size_t)BT * 384;       // [HID][BT]  (V^T)
    unsigned short* ybb = vtg + (size_t)HID * BT;       // [BT][HID]

    dim3 blk(256);
    cvt_all<<<dim3(5664), blk, 0, stream>>>(hs, Wq, Wk, Wv, Wo, hsb, wqk, wvb, wob);

    // fused Q/K projection + V^T projection
    proj_qkv<<<dim3(480), blk, 0, stream>>>(hsb, wqk, wvb, qkb, vtg);

    based_attn_mfma<<<dim3(T / 64 * NH * B * 2), blk, 0, stream>>>(qkb, vtg, ybb);

    // output projection (fp32 out)
    proj_out<<<dim3(12, 32), blk, 0, stream>>>(ybb, wob, out);
}

// Round 7
// 214.653 us; speedup vs baseline: 8.0921x; 1.0082x over previous
//
#include <hip/hip_runtime.h>

#define B 2
#define T 2048
#define HID 1536
#define NH 12
#define DK 16
#define DV 128
#define BT (B * T)
#define EPS 1e-12f

typedef __attribute__((ext_vector_type(8))) short bf16x8;
typedef __attribute__((ext_vector_type(4))) float f32x4;

__device__ __forceinline__ unsigned short f2bf(float f) {
    unsigned int u = __float_as_uint(f);
    u += 0x7FFFu + ((u >> 16) & 1u);
    return (unsigned short)(u >> 16);
}

// ---------------------------------------------------------------------------
// Fused fp32->bf16 for all 5 inputs. Segments in 2048-element blocks:
// hs 3072 | Wq 144 | Wk 144 | Wv 1152 | Wo 1152 = 5664 blocks.
// Wq+Wk land concatenated in wqk [384][1536].
// ---------------------------------------------------------------------------
__global__ __launch_bounds__(256) void cvt_all(const float* __restrict__ hs,
                                               const float* __restrict__ Wq,
                                               const float* __restrict__ Wk,
                                               const float* __restrict__ Wv,
                                               const float* __restrict__ Wo,
                                               unsigned short* __restrict__ hsb,
                                               unsigned short* __restrict__ wqk,
                                               unsigned short* __restrict__ wvb,
                                               unsigned short* __restrict__ wob) {
    int bx = blockIdx.x;
    const float* src;
    unsigned short* dst;
    if (bx < 3072)      { src = hs; dst = hsb; }
    else if (bx < 3216) { src = Wq; dst = wqk;          bx -= 3072; }
    else if (bx < 3360) { src = Wk; dst = wqk + 294912; bx -= 3216; }
    else if (bx < 4512) { src = Wv; dst = wvb;          bx -= 3360; }
    else                { src = Wo; dst = wob;          bx -= 4512; }
    const int i = (bx * 256 + threadIdx.x) * 8;
    float4 a = *(const float4*)(src + i);
    float4 b = *(const float4*)(src + i + 4);
    *(ushort4*)(dst + i)     = make_ushort4(f2bf(a.x), f2bf(a.y), f2bf(a.z), f2bf(a.w));
    *(ushort4*)(dst + i + 4) = make_ushort4(f2bf(b.x), f2bf(b.y), f2bf(b.z), f2bf(b.w));
}

// ---------------------------------------------------------------------------
// Generic m97-style 128x128 bf16 GEMM tile body (BK=32, global_load_lds w=16,
// 16x16x32 MFMA, 4 waves x 4x4 frags). C bf16 row-major, no store guards
// (M,N multiples of 128).
// ---------------------------------------------------------------------------
__device__ __forceinline__ void gemm_tile_bf16(const unsigned short* __restrict__ A,
                                               const unsigned short* __restrict__ Bm,
                                               unsigned short* __restrict__ C,
                                               int m0, int n0, int K, int ldc,
                                               unsigned short* As, unsigned short* Bs) {
    const int tid = threadIdx.x;
    const int wave = tid >> 6, lane = tid & 63;
    const int wm = (wave & 1) * 64, wn = (wave >> 1) * 64;
    const int fr = lane & 15;
    const int fk = (lane >> 4) * 8;

    f32x4 acc[4][4];
#pragma unroll
    for (int i = 0; i < 4; ++i)
#pragma unroll
        for (int j = 0; j < 4; ++j) acc[i][j] = (f32x4)0.f;

    const int c0 = tid, c1 = tid + 256;
    const int r0 = c0 >> 2, q0 = (c0 & 3) * 8;
    const int r1 = c1 >> 2, q1 = (c1 & 3) * 8;

    for (int k0 = 0; k0 < K; k0 += 32) {
        __builtin_amdgcn_global_load_lds(
            (const __attribute__((address_space(1))) void*)(A + (size_t)(m0 + r0) * K + k0 + q0),
            (__attribute__((address_space(3))) void*)(As + c0 * 8), 16, 0, 0);
        __builtin_amdgcn_global_load_lds(
            (const __attribute__((address_space(1))) void*)(A + (size_t)(m0 + r1) * K + k0 + q1),
            (__attribute__((address_space(3))) void*)(As + c1 * 8), 16, 0, 0);
        __builtin_amdgcn_global_load_lds(
            (const __attribute__((address_space(1))) void*)(Bm + (size_t)(n0 + r0) * K + k0 + q0),
            (__attribute__((address_space(3))) void*)(Bs + c0 * 8), 16, 0, 0);
        __builtin_amdgcn_global_load_lds(
            (const __attribute__((address_space(1))) void*)(Bm + (size_t)(n0 + r1) * K + k0 + q1),
            (__attribute__((address_space(3))) void*)(Bs + c1 * 8), 16, 0, 0);
        __syncthreads();

        bf16x8 af[4], bfr[4];
#pragma unroll
        for (int mb = 0; mb < 4; ++mb)
            af[mb] = *(const bf16x8*)(As + (wm + mb * 16 + fr) * 32 + fk);
#pragma unroll
        for (int nb = 0; nb < 4; ++nb)
            bfr[nb] = *(const bf16x8*)(Bs + (wn + nb * 16 + fr) * 32 + fk);
#pragma unroll
        for (int mb = 0; mb < 4; ++mb)
#pragma unroll
            for (int nb = 0; nb < 4; ++nb)
                acc[mb][nb] = __builtin_amdgcn_mfma_f32_16x16x32_bf16(
                    af[mb], bfr[nb], acc[mb][nb], 0, 0, 0);
        __syncthreads();
    }

    const int orow = (lane >> 4) * 4;
#pragma unroll
    for (int nb = 0; nb < 4; ++nb) {
        const int col = n0 + wn + nb * 16 + fr;
#pragma unroll
        for (int mb = 0; mb < 4; ++mb) {
            const int row = m0 + wm + mb * 16 + orow;
#pragma unroll
            for (int r = 0; r < 4; ++r)
                C[(size_t)(row + r) * ldc + col] = f2bf(acc[mb][nb][r]);
        }
    }
}

// ---------------------------------------------------------------------------
// Fused QK-proj + V^T-proj, one launch, 480 blocks:
//   bx <  96: qk[BT][384] = hsb @ wqk^T           (m-tile bx/3, n-tile bx%3)
//   bx >= 96: vt[HID][BT] = wvb @ hsb^T (V^T)      (4-wide n-supertile swizzle)
// ---------------------------------------------------------------------------
__global__ __launch_bounds__(256) void proj_qkv(const unsigned short* __restrict__ hsb,
                                                const unsigned short* __restrict__ wqk,
                                                const unsigned short* __restrict__ wvb,
                                                unsigned short* __restrict__ qkb,
                                                unsigned short* __restrict__ vtg) {
    __shared__ unsigned short As[128 * 32];
    __shared__ unsigned short Bs[128 * 32];
    const int bx = blockIdx.x;
    if (bx < 96) {
        gemm_tile_bf16(hsb, wqk, qkb, (bx / 3) * 128, (bx % 3) * 128, HID, 384, As, Bs);
    } else {
        const int vid = bx - 96;
        const int grp = vid / 48, sub = vid % 48;
        const int n_t = grp * 4 + (sub & 3), m_t = sub >> 2;
        gemm_tile_bf16(wvb, hsb, vtg, m_t * 128, n_t * 128, HID, BT, As, Bs);
    }
}

// ---------------------------------------------------------------------------
// Output projection: out[BT][HID] fp32 = ybb @ wob^T.
// ---------------------------------------------------------------------------
__global__ __launch_bounds__(256) void proj_out(const unsigned short* __restrict__ A,
                                                const unsigned short* __restrict__ Bm,
                                                float* __restrict__ C) {
    __shared__ unsigned short As[128 * 32];
    __shared__ unsigned short Bs[128 * 32];
    const int tid = threadIdx.x;
    const int m0 = blockIdx.y * 128;
    const int n0 = blockIdx.x * 128;
    const int wave = tid >> 6, lane = tid & 63;
    const int wm = (wave & 1) * 64, wn = (wave >> 1) * 64;
    const int fr = lane & 15;
    const int fk = (lane >> 4) * 8;
    const int K = HID;

    f32x4 acc[4][4];
#pragma unroll
    for (int i = 0; i < 4; ++i)
#pragma unroll
        for (int j = 0; j < 4; ++j) acc[i][j] = (f32x4)0.f;

    const int c0 = tid, c1 = tid + 256;
    const int r0 = c0 >> 2, q0 = (c0 & 3) * 8;
    const int r1 = c1 >> 2, q1 = (c1 & 3) * 8;

    for (int k0 = 0; k0 < K; k0 += 32) {
        __builtin_amdgcn_global_load_lds(
            (const __attribute__((address_space(1))) void*)(A + (size_t)(m0 + r0) * K + k0 + q0),
            (__attribute__((address_space(3))) void*)(As + c0 * 8), 16, 0, 0);
        __builtin_amdgcn_global_load_lds(
            (const __attribute__((address_space(1))) void*)(A + (size_t)(m0 + r1) * K + k0 + q1),
            (__attribute__((address_space(3))) void*)(As + c1 * 8), 16, 0, 0);
        __builtin_amdgcn_global_load_lds(
            (const __attribute__((address_space(1))) void*)(Bm + (size_t)(n0 + r0) * K + k0 + q0),
            (__attribute__((address_space(3))) void*)(Bs + c0 * 8), 16, 0, 0);
        __builtin_amdgcn_global_load_lds(
            (const __attribute__((address_space(1))) void*)(Bm + (size_t)(n0 + r1) * K + k0 + q1),
            (__attribute__((address_space(3))) void*)(Bs + c1 * 8), 16, 0, 0);
        __syncthreads();

        bf16x8 af[4], bfr[4];
#pragma unroll
        for (int mb = 0; mb < 4; ++mb)
            af[mb] = *(const bf16x8*)(As + (wm + mb * 16 + fr) * 32 + fk);
#pragma unroll
        for (int nb = 0; nb < 4; ++nb)
            bfr[nb] = *(const bf16x8*)(Bs + (wn + nb * 16 + fr) * 32 + fk);
#pragma unroll
        for (int mb = 0; mb < 4; ++mb)
#pragma unroll
            for (int nb = 0; nb < 4; ++nb)
                acc[mb][nb] = __builtin_amdgcn_mfma_f32_16x16x32_bf16(
                    af[mb], bfr[nb], acc[mb][nb], 0, 0, 0);
        __syncthreads();
    }

    const int orow = (lane >> 4) * 4;
#pragma unroll
    for (int nb = 0; nb < 4; ++nb) {
        const int col = n0 + wn + nb * 16 + fr;
#pragma unroll
        for (int mb = 0; mb < 4; ++mb) {
            const int row = m0 + wm + mb * 16 + orow;
#pragma unroll
            for (int r = 0; r < 4; ++r)
                C[(size_t)(row + r) * HID + col] = acc[mb][nb][r];
        }
    }
}

// ---------------------------------------------------------------------------
// MFMA causal Taylor linear attention, software-pipelined.
//   S^T = K Q^T ; S = 1 + a/4 + a^2/32, causal mask on diag tile only
//   O^T = V^T S^T ; y = O^T/den
// Pipelining: kt+1's K/V^T fragments are issued before tile kt's compute, so
// their ~250-cyc latency overlaps S-MFMA + poly + barrier + O-MFMA.
// K-frag load is de-predicated (clamped column): upper-quad k>=16 garbage is
// annihilated by the zeroed Q B-frag. S stored to LDS via trunc bit-pack.
// 768 blocks, qt-major heavy-first.
// ---------------------------------------------------------------------------
__global__ __launch_bounds__(256) void based_attn_mfma(const unsigned short* __restrict__ qk,
                                                       const unsigned short* __restrict__ vt,
                                                       unsigned short* __restrict__ yb) {
    const int bx = blockIdx.x;
    const int qt = (T / 64 - 1) - (bx / (NH * B));
    const int hb = bx % (NH * B);
    const int h  = hb >> 1;
    const int bi = hb & 1;
    const int tid = threadIdx.x;
    const int wave = tid >> 6, lane = tid & 63;
    const int fr = lane & 15, quad = lane >> 4;
    const int fk = quad * 8;
    const int fkk = (quad & 1) * 8;   // clamped column for K A-frag (in-bounds)

    __shared__ __attribute__((aligned(16))) unsigned short ss[2][64][72];
    __shared__ float den_lds[64];
    if (tid < 64) den_lds[tid] = 0.f;

    const bf16x8 zf = {};
    // persistent Q B-frags: B[k][n] = Q[n=i][k], i = nt*16+fr; k>=16 zeroed
    bf16x8 qf[4];
#pragma unroll
    for (int nt = 0; nt < 4; ++nt) {
        qf[nt] = zf;
        if (quad < 2)
            qf[nt] = *(const bf16x8*)&qk[(size_t)(bi * T + qt * 64 + nt * 16 + fr) * 384
                                         + h * DK + fk];
    }

    f32x4 oacc[2][4];
#pragma unroll
    for (int mt = 0; mt < 2; ++mt)
#pragma unroll
        for (int nt = 0; nt < 4; ++nt) oacc[mt][nt] = (f32x4)0.f;
    float denp[4] = {0.f, 0.f, 0.f, 0.f};

    // base pointers (row 0 of this block's slice)
    const unsigned short* kbase = qk + (size_t)(bi * T + wave * 16 + fr) * 384 + 192 + h * DK + fkk;
    const unsigned short* vbase0 = vt + (size_t)(h * DV + wave * 32 + fr) * BT + bi * T + fk;
    const unsigned short* vbase1 = vbase0 + (size_t)16 * BT;

    // prologue: prefetch kt=0
    bf16x8 kf_n = *(const bf16x8*)kbase;
    bf16x8 vf_n[2][2];
    vf_n[0][0] = *(const bf16x8*)(vbase0);
    vf_n[0][1] = *(const bf16x8*)(vbase0 + 32);
    vf_n[1][0] = *(const bf16x8*)(vbase1);
    vf_n[1][1] = *(const bf16x8*)(vbase1 + 32);

    for (int kt = 0; kt <= qt; ++kt) {
        const int bsel = kt & 1;
        const bf16x8 kf = kf_n;
        bf16x8 vf[2][2];
        vf[0][0] = vf_n[0][0]; vf[0][1] = vf_n[0][1];
        vf[1][0] = vf_n[1][0]; vf[1][1] = vf_n[1][1];

        // prefetch kt+1 (clamped on last iteration; redundant but in-bounds)
        {
            const int ktn = (kt < qt) ? kt + 1 : qt;
            kf_n = *(const bf16x8*)(kbase + (size_t)ktn * 64 * 384);
            const int off = ktn * 64;
            vf_n[0][0] = *(const bf16x8*)(vbase0 + off);
            vf_n[0][1] = *(const bf16x8*)(vbase0 + off + 32);
            vf_n[1][0] = *(const bf16x8*)(vbase1 + off);
            vf_n[1][1] = *(const bf16x8*)(vbase1 + off + 32);
        }

        // S^T: wave owns j-strip [wave*16, wave*16+16)
        f32x4 sa[4];
#pragma unroll
        for (int nt = 0; nt < 4; ++nt)
            sa[nt] = __builtin_amdgcn_mfma_f32_16x16x32_bf16(kf, qf[nt], (f32x4)0.f, 0, 0, 0);

#pragma unroll
        for (int nt = 0; nt < 4; ++nt) {
            const int i = nt * 16 + fr;
            float sv[4];
#pragma unroll
            for (int r = 0; r < 4; ++r) {
                const float a = sa[nt][r];
                sv[r] = fmaf(a, fmaf(a, 1.f / 32.f, 0.25f), 1.f);
            }
            if (kt == qt) {   // wave-uniform: causal mask only on diag tile
#pragma unroll
                for (int r = 0; r < 4; ++r) {
                    const int j = wave * 16 + quad * 4 + r;
                    if (j > i) sv[r] = 0.f;
                }
            }
            denp[nt] += sv[0] + sv[1] + sv[2] + sv[3];
            uint2 pk;
            pk.x = (__float_as_uint(sv[0]) >> 16) | (__float_as_uint(sv[1]) & 0xFFFF0000u);
            pk.y = (__float_as_uint(sv[2]) >> 16) | (__float_as_uint(sv[3]) & 0xFFFF0000u);
            *(uint2*)&ss[bsel][i][wave * 16 + quad * 4] = pk;
        }
        __syncthreads();

        // O^T += V^T S^T : wave owns c-chunk [wave*32, wave*32+32)
#pragma unroll
        for (int k2 = 0; k2 < 2; ++k2) {
            bf16x8 sf[4];
#pragma unroll
            for (int nt = 0; nt < 4; ++nt)
                sf[nt] = *(const bf16x8*)&ss[bsel][nt * 16 + fr][k2 * 32 + fk];
#pragma unroll
            for (int mt = 0; mt < 2; ++mt)
#pragma unroll
                for (int nt = 0; nt < 4; ++nt)
                    oacc[mt][nt] = __builtin_amdgcn_mfma_f32_16x16x32_bf16(
                        vf[mt][k2], sf[nt], oacc[mt][nt], 0, 0, 0);
        }
    }

    // den: quad-reduce (same fr), then cross-wave via LDS atomics
#pragma unroll
    for (int nt = 0; nt < 4; ++nt) {
        float v = denp[nt];
        v += __shfl_xor(v, 16);
        v += __shfl_xor(v, 32);
        if (quad == 0) atomicAdd(&den_lds[nt * 16 + fr], v);
    }
    __syncthreads();

    // y[i][c] = O^T[c][i] / den[i], bf16 row-major [BT][HID]
#pragma unroll
    for (int nt = 0; nt < 4; ++nt) {
        const int i = nt * 16 + fr;
        const float rd = 1.f / (den_lds[i] + EPS);
        const size_t rowbase = (size_t)(bi * T + qt * 64 + i) * (NH * DV) + h * DV;
#pragma unroll
        for (int mt = 0; mt < 2; ++mt) {
            const int c = wave * 32 + mt * 16 + quad * 4;
            const f32x4 o = oacc[mt][nt];
            *(ushort4*)&yb[rowbase + c] = make_ushort4(f2bf(o[0] * rd), f2bf(o[1] * rd),
                                                       f2bf(o[2] * rd), f2bf(o[3] * rd));
        }
    }
}

extern "C" void kernel_launch(void* const* d_in, const int* in_sizes, int n_in,
                              void* d_out, int out_size, void* d_ws, size_t ws_size,
                              hipStream_t stream) {
    (void)in_sizes; (void)n_in; (void)out_size; (void)ws_size;
    const float* hs = (const float*)d_in[0];
    const float* Wq = (const float*)d_in[1];
    const float* Wk = (const float*)d_in[2];
    const float* Wv = (const float*)d_in[3];
    const float* Wo = (const float*)d_in[4];
    float* out = (float*)d_out;

    // bf16 workspace (~51.5 MB)
    unsigned short* hsb = (unsigned short*)d_ws;        // [BT][HID]
    unsigned short* wqk = hsb + (size_t)BT * HID;       // [384][HID]  (Wq ; Wk)
    unsigned short* wvb = wqk + (size_t)384 * HID;      // [HID][HID]
    unsigned short* wob = wvb + (size_t)HID * HID;      // [HID][HID]
    unsigned short* qkb = wob + (size_t)HID * HID;      // [BT][384]
    unsigned short* vtg = qkb + (size_t)BT * 384;       // [HID][BT]  (V^T)
    unsigned short* ybb = vtg + (size_t)HID * BT;       // [BT][HID]

    dim3 blk(256);
    cvt_all<<<dim3(5664), blk, 0, stream>>>(hs, Wq, Wk, Wv, Wo, hsb, wqk, wvb, wob);

    // fused Q/K projection + V^T projection
    proj_qkv<<<dim3(480), blk, 0, stream>>>(hsb, wqk, wvb, qkb, vtg);

    based_attn_mfma<<<dim3(T / 64 * NH * B), blk, 0, stream>>>(qkb, vtg, ybb);

    // output projection (fp32 out)
    proj_out<<<dim3(12, 32), blk, 0, stream>>>(ybb, wob, out);
}